// Round 14
// baseline (278.163 us; speedup 1.0000x reference)
//
#include <hip/hip_runtime.h>
#include <hip/hip_bf16.h>

typedef _Float16 h8 __attribute__((ext_vector_type(8)));
typedef float f4 __attribute__((ext_vector_type(4)));

#define N_TOK 65536
#define DIM 256
#define KCODES 1024
#define HWSZ 4096

// async global->LDS, 16B per lane. LDS dest = wave-uniform base + lane*16.
__device__ __forceinline__ void gll16(const void* g, void* l) {
    __builtin_amdgcn_global_load_lds((const __attribute__((address_space(1))) void*)g,
                                     (__attribute__((address_space(3))) void*)l, 16, 0, 0);
}

// Fragment layout (A and B operands, 16x16x32 f16 MFMA):
//   element (n, d) -> granule G = ((n>>4)*8 + (d>>5))*64 + ((d>>3)&3)*16 + (n&15),
//   half j = d&7 inside the 16B granule. Conflict-free ds_read_b128, linear gll16.

// ---------------- K0a: embedding -> fragment-layout fp16 hi/lo ---------------
__global__ void k_prep_frag(const float* __restrict__ emb, _Float16* __restrict__ BhF,
                            _Float16* __restrict__ BlF) {
    int gi = blockIdx.x * 256 + threadIdx.x;
    int kb = gi >> 9, s = (gi >> 6) & 7, dq = (gi >> 4) & 3, r = gi & 15;
    int code = kb * 16 + r;
    const float* src = emb + (size_t)code * DIM + s * 32 + dq * 8;
    float4 x0 = *(const float4*)(src);
    float4 x1 = *(const float4*)(src + 4);
    float xs[8] = {x0.x, x0.y, x0.z, x0.w, x1.x, x1.y, x1.z, x1.w};
    h8 hi, lo;
#pragma unroll
    for (int j = 0; j < 8; ++j) {
        _Float16 h = (_Float16)xs[j];
        hi[j] = h;
        lo[j] = (_Float16)(xs[j] - (float)h);
    }
    *(h8*)(BhF + (size_t)gi * 8) = hi;
    *(h8*)(BlF + (size_t)gi * 8) = lo;
}

// ---------------- K0b: e_sq ---------------------------------------------------
__global__ void k_esq(const float* __restrict__ emb, float* __restrict__ e_sq) {
    int t = threadIdx.x;
    int code = blockIdx.x * 4 + (t >> 6);
    int l = t & 63;
    float4 v = *(const float4*)(emb + (size_t)code * DIM + l * 4);
    float s = v.x * v.x + v.y * v.y + v.z * v.z + v.w * v.w;
#pragma unroll
    for (int off = 32; off >= 1; off >>= 1) s += __shfl_xor(s, off);
    if (l == 0) e_sq[code] = s;
}

// ------- K1: transpose z[B,C,H,W] -> enc[N,C] + fragment fp16 hi/lo ----------
__global__ void k_transpose(const float* __restrict__ z, float* __restrict__ enc,
                            _Float16* __restrict__ AhF, _Float16* __restrict__ AlF) {
    __shared__ float T[64][65];
    int blk = blockIdx.x;
    int b = blk >> 8;
    int rem = blk & 255;
    int c0 = (rem >> 6) * 64;
    int hw0 = (rem & 63) * 64;
    int t = threadIdx.x;
    const float* zp = z + (size_t)b * DIM * HWSZ;
    {
        int hw4 = (t & 15) * 4, cl = t >> 4;
#pragma unroll
        for (int i = 0; i < 4; ++i) {
            int c = cl + i * 16;
            float4 v = *(const float4*)(zp + (size_t)(c0 + c) * HWSZ + hw0 + hw4);
            T[c][hw4 + 0] = v.x; T[c][hw4 + 1] = v.y;
            T[c][hw4 + 2] = v.z; T[c][hw4 + 3] = v.w;
        }
    }
    __syncthreads();
    {
        int c4 = (t & 15) * 4, hwl = t >> 4;
#pragma unroll
        for (int i = 0; i < 4; ++i) {
            int hw = hwl + i * 16;
            float4 v;
            v.x = T[c4 + 0][hw]; v.y = T[c4 + 1][hw];
            v.z = T[c4 + 2][hw]; v.w = T[c4 + 3][hw];
            *(float4*)(enc + (size_t)(b * HWSZ + hw0 + hw) * DIM + c0 + c4) = v;
        }
    }
    {
        int base_nb = b * 256 + (hw0 >> 4);
#pragma unroll
        for (int i = 0; i < 2; ++i) {
            int gidx = i * 256 + t;
            int nbi = gidx >> 7, si = (gidx >> 6) & 1, dq = (gidx >> 4) & 3, r = gidx & 15;
            int hwl = nbi * 16 + r;
            int cl = si * 32 + dq * 8;
            h8 hi, lo;
#pragma unroll
            for (int j = 0; j < 8; ++j) {
                float x = T[cl + j][hwl];
                _Float16 h = (_Float16)x;
                hi[j] = h;
                lo[j] = (_Float16)(x - (float)h);
            }
            size_t G = (((size_t)(base_nb + nbi) * 8) + (c0 >> 5) + si) * 64 + dq * 16 + r;
            *(h8*)(AhF + G * 8) = hi;
            *(h8*)(AlF + G * 8) = lo;
        }
    }
}

// ---- K2: GEMM, read-ahead pipeline: regs for chunk c loaded during c-1 ------
// virtual K = 24 chunks of K32 (8 hh, 8 hl, 8 lh). 5-slot x 32KB LDS ring
// (160 KB): compute c, read-ahead c+1, stage c+4. One barrier per chunk,
// counted vmcnt(8) (2-chunk slack), counted lgkmcnt(12).
#define WAITV(n) asm volatile("s_waitcnt vmcnt(" #n ")" ::: "memory")
#define LGKM(n) asm volatile("s_waitcnt lgkmcnt(" #n ")" ::: "memory")
#define BARRIER __builtin_amdgcn_s_barrier()
#define PRIO1 __builtin_amdgcn_s_setprio(1)
#define PRIO0 __builtin_amdgcn_s_setprio(0)
#define SGB0 __builtin_amdgcn_sched_barrier(0)

extern __shared__ char SB[];

__global__ __launch_bounds__(512, 2)
void k_gemm_argmin(const _Float16* __restrict__ AhF, const _Float16* __restrict__ AlF,
                   const _Float16* __restrict__ BhF, const _Float16* __restrict__ BlF,
                   const float* __restrict__ e_sq,
                   float* __restrict__ pV1, int* __restrict__ pI1) {
    int gid = blockIdx.x;
    // rchunk-major: 8-MB A chunks (32 rowTiles) reused across all 4 colTiles
    int grp = gid >> 7;
    int colTile = (gid >> 5) & 3;
    int rowTile = grp * 32 + (gid & 31);
    int r0 = rowTile * 256, c0 = colTile * 256;
    int t = threadIdx.x;
    int w = t >> 6, l = t & 63;           // 8 waves
    int wm = w >> 2, wn = w & 3;          // wave tile 128 rows x 64 cols
    int l16 = l & 15, lhi = l >> 4;

    const char* gAh = (const char*)AhF + (((size_t)(rowTile * 16 + 2 * w)) << 13) + (l << 4);
    const char* gAl = (const char*)AlF + (((size_t)(rowTile * 16 + 2 * w)) << 13) + (l << 4);
    const char* gBh = (const char*)BhF + (((size_t)(colTile * 16 + 2 * w)) << 13) + (l << 4);
    const char* gBl = (const char*)BlF + (((size_t)(colTile * 16 + 2 * w)) << 13) + (l << 4);

// stage chunk c (pass c>>3, d-step c&7) into slot c%5: 4 gll16 per wave
#define ISSUE(c) do { \
    const char* a_ = (((c) >> 3) == 2) ? gAl : gAh; \
    const char* b_ = (((c) >> 3) == 1) ? gBl : gBh; \
    const int so_ = ((c) & 7) << 10; \
    char* sp_ = SB + ((c) % 5) * 32768; \
    gll16(a_ + so_, sp_ + ((2 * w) << 10)); \
    gll16(a_ + 8192 + so_, sp_ + ((2 * w + 1) << 10)); \
    gll16(b_ + so_, sp_ + 16384 + ((2 * w) << 10)); \
    gll16(b_ + 8192 + so_, sp_ + 16384 + ((2 * w + 1) << 10)); \
} while (0)

// read chunk c's fragments (slot c%5) into register set (aX, bX): 12 ds_read
#define READ(c, aX, bX) { const char* bp_ = SB + ((c) % 5) * 32768; \
    _Pragma("unroll") for (int mf = 0; mf < 8; ++mf) \
        aX[mf] = *(const h8*)(bp_ + ((wm * 8 + mf) << 10) + (l << 4)); \
    _Pragma("unroll") for (int nf = 0; nf < 4; ++nf) \
        bX[nf] = *(const h8*)(bp_ + 16384 + ((wn * 4 + nf) << 10) + (l << 4)); }

#define MFMA32(A_, B_) { _Pragma("unroll") for (int mf = 0; mf < 8; ++mf) \
    _Pragma("unroll") for (int nf = 0; nf < 4; ++nf) \
        acc[mf][nf] = __builtin_amdgcn_mfma_f32_16x16x32_f16(A_[mf], B_[nf], acc[mf][nf], 0, 0, 0); }

// body(c): READ(c+1) -> ISSUE(c+4) -> lgkm(LG) -> MFMA(c) -> vmcnt(WV) -> barrier
#define CHUNK(c, AC, BC, AN, BN, WV, LG) \
    if ((c) < 23) { READ((c) + 1, AN, BN); } \
    if ((c) < 20) { ISSUE((c) + 4); } \
    LGKM(LG); SGB0; \
    PRIO1; MFMA32(AC, BC); PRIO0; \
    WAITV(WV); BARRIER;

    f4 acc[8][4];
#pragma unroll
    for (int i = 0; i < 8; ++i)
#pragma unroll
        for (int j = 0; j < 4; ++j) acc[i][j] = (f4)0.0f;

    h8 aA[8], bA[4], aB[8], bB[4];

    // prologue: chunks 0..3 staged; confirm 0,1 done; pre-read chunk 0
    ISSUE(0); ISSUE(1); ISSUE(2); ISSUE(3);
    WAITV(8); BARRIER;
    READ(0, aA, bA);

    CHUNK(0, aA, bA, aB, bB, 8, 12)   CHUNK(1, aB, bB, aA, bA, 8, 12)
    CHUNK(2, aA, bA, aB, bB, 8, 12)   CHUNK(3, aB, bB, aA, bA, 8, 12)
    CHUNK(4, aA, bA, aB, bB, 8, 12)   CHUNK(5, aB, bB, aA, bA, 8, 12)
    CHUNK(6, aA, bA, aB, bB, 8, 12)   CHUNK(7, aB, bB, aA, bA, 8, 12)
    CHUNK(8, aA, bA, aB, bB, 8, 12)   CHUNK(9, aB, bB, aA, bA, 8, 12)
    CHUNK(10, aA, bA, aB, bB, 8, 12)  CHUNK(11, aB, bB, aA, bA, 8, 12)
    CHUNK(12, aA, bA, aB, bB, 8, 12)  CHUNK(13, aB, bB, aA, bA, 8, 12)
    CHUNK(14, aA, bA, aB, bB, 8, 12)  CHUNK(15, aB, bB, aA, bA, 8, 12)
    CHUNK(16, aA, bA, aB, bB, 8, 12)  CHUNK(17, aB, bB, aA, bA, 8, 12)
    CHUNK(18, aA, bA, aB, bB, 8, 12)  CHUNK(19, aB, bB, aA, bA, 8, 12)
    CHUNK(20, aA, bA, aB, bB, 4, 12)  CHUNK(21, aB, bB, aA, bA, 0, 12)
    CHUNK(22, aA, bA, aB, bB, 0, 12)  CHUNK(23, aB, bB, aA, bA, 0, 0)

    // ---- scores + per-row argmin over this block's 256 codes ----
    float* smV = (float*)SB;          // [4][256] — slot0 reads long done
    int* smI = (int*)(SB + 4096);     // [4][256]

    float esq[4];
#pragma unroll
    for (int nf = 0; nf < 4; ++nf) esq[nf] = e_sq[c0 + wn * 64 + nf * 16 + l16];

#pragma unroll
    for (int mf = 0; mf < 8; ++mf) {
#pragma unroll
        for (int rg = 0; rg < 4; ++rg) {
            float bestV = 3.4e38f;
            int bestI = 0;
#pragma unroll
            for (int nf = 0; nf < 4; ++nf) {
                float v = esq[nf] - 2.0f * acc[mf][nf][rg];
                int ci = c0 + wn * 64 + nf * 16 + l16;
                if (v < bestV || (v == bestV && ci < bestI)) { bestV = v; bestI = ci; }
            }
#pragma unroll
            for (int off = 1; off < 16; off <<= 1) {
                float vv = __shfl_xor(bestV, off);
                int ii = __shfl_xor(bestI, off);
                if (vv < bestV || (vv == bestV && ii < bestI)) { bestV = vv; bestI = ii; }
            }
            if (l16 == 0) {
                int rloc = wm * 128 + mf * 16 + lhi * 4 + rg;
                smV[wn * 256 + rloc] = bestV;
                smI[wn * 256 + rloc] = bestI;
            }
        }
    }
    __syncthreads();
    if (t < 256) {
        float bestV = smV[t];
        int bestI = smI[t];
#pragma unroll
        for (int wn2 = 1; wn2 < 4; ++wn2) {
            float v = smV[wn2 * 256 + t];
            int i2 = smI[wn2 * 256 + t];
            if (v < bestV || (v == bestV && i2 < bestI)) { bestV = v; bestI = i2; }
        }
        pV1[colTile * N_TOK + r0 + t] = bestV;
        pI1[colTile * N_TOK + r0 + t] = bestI;
    }
}

// ---- K3: fused epilogue: combine -> out2, gather out1, transpose out3 -------
__global__ void k_final_all(const float* __restrict__ pV1, const int* __restrict__ pI1,
                            const float* __restrict__ emb,
                            float* __restrict__ out2, float* __restrict__ out1,
                            float* __restrict__ out3) {
    __shared__ int sidx[256];
    __shared__ float E[32][257];
    int t = threadIdx.x;
    int n0 = blockIdx.x * 256;
    int n = n0 + t;
    float v1 = pV1[n];
    int i1 = pI1[n];
#pragma unroll
    for (int ct = 1; ct < 4; ++ct) {
        float a1 = pV1[ct * N_TOK + n];
        int ai = pI1[ct * N_TOK + n];
        if (a1 < v1 || (a1 == v1 && ai < i1)) { v1 = a1; i1 = ai; }
    }
    out2[n] = (float)i1;
    sidx[t] = i1;
    __syncthreads();
    {
        int rr = t >> 2, q = t & 3;
#pragma unroll
        for (int i = 0; i < 4; ++i) {
            int r = i * 64 + rr;
            int idx = sidx[r];
            const float* src = emb + (size_t)idx * DIM + q * 64;
            float* dst = out1 + (size_t)(n0 + r) * DIM + q * 64;
#pragma unroll
            for (int j = 0; j < 16; ++j)
                *(float4*)(dst + j * 4) = *(const float4*)(src + j * 4);
        }
    }
    int b = n0 >> 12;
    int hw0b = n0 & 4095;
    for (int sub = 0; sub < 8; ++sub) {
        __syncthreads();
        {
            int r = t >> 3, oct = t & 7;
            int idx = sidx[sub * 32 + r];
            const float* src = emb + (size_t)idx * DIM + oct * 32;
#pragma unroll
            for (int i = 0; i < 8; ++i) {
                float4 v = *(const float4*)(src + i * 4);
                E[r][oct * 32 + i * 4 + 0] = v.x;
                E[r][oct * 32 + i * 4 + 1] = v.y;
                E[r][oct * 32 + i * 4 + 2] = v.z;
                E[r][oct * 32 + i * 4 + 3] = v.w;
            }
        }
        __syncthreads();
        {
            int w = t >> 6, l = t & 63;
            int ch = l >> 5, hw = l & 31;
            float* dst = out3 + (size_t)b * DIM * HWSZ + hw0b + sub * 32 + hw;
#pragma unroll
            for (int it = 0; it < 32; ++it) {
                int c = w * 64 + it * 2 + ch;
                dst[(size_t)c * HWSZ] = E[hw][c];
            }
        }
    }
}

extern "C" void kernel_launch(void* const* d_in, const int* in_sizes, int n_in,
                              void* d_out, int out_size, void* d_ws, size_t ws_size,
                              hipStream_t stream) {
    const float* z = (const float*)d_in[0];
    const float* emb = (const float*)d_in[1];
    float* out = (float*)d_out;
    float* out0 = out;                    // encoded_flat  [65536,256]
    float* out1 = out + 16777216;         // quantized_flat[65536,256]
    float* out2 = out + 33554432;         // indices       [65536] (as float)
    float* out3 = out + 33619968;         // quantized     [16,256,64,64]

    // A-operand fp16 hi/lo scratch fills the out1 region (64 MB); out1 is
    // written afterwards by k_final_all.
    _Float16* AhF = (_Float16*)out1;
    _Float16* AlF = (_Float16*)(out1 + 8388608);

    char* ws = (char*)d_ws;
    _Float16* BhF = (_Float16*)(ws);                 // 512 KB
    _Float16* BlF = (_Float16*)(ws + 524288);        // 512 KB
    float* e_sq = (float*)(ws + 1048576);            // 4 KB
    float* pV1 = (float*)(ws + 1052672);             // 1 MB
    int* pI1 = (int*)(ws + 2101248);                 // 1 MB

    hipFuncSetAttribute((const void*)k_gemm_argmin,
                        hipFuncAttributeMaxDynamicSharedMemorySize, 163840);

    k_prep_frag<<<128, 256, 0, stream>>>(emb, BhF, BlF);
    k_esq<<<256, 256, 0, stream>>>(emb, e_sq);
    k_transpose<<<4096, 256, 0, stream>>>(z, out0, AhF, AlF);
    k_gemm_argmin<<<1024, 512, 163840, stream>>>(AhF, AlF, BhF, BlF, e_sq, pV1, pI1);
    k_final_all<<<256, 256, 0, stream>>>(pV1, pI1, emb, out2, out1, out3);
}

// Round 15
// 240.412 us; speedup vs baseline: 1.1570x; 1.1570x over previous
//
#include <hip/hip_runtime.h>
#include <hip/hip_bf16.h>

typedef _Float16 h8 __attribute__((ext_vector_type(8)));
typedef float f4 __attribute__((ext_vector_type(4)));

#define N_TOK 65536
#define DIM 256
#define KCODES 1024
#define HWSZ 4096

// async global->LDS, 16B per lane. LDS dest = wave-uniform base + lane*16.
__device__ __forceinline__ void gll16(const void* g, void* l) {
    __builtin_amdgcn_global_load_lds((const __attribute__((address_space(1))) void*)g,
                                     (__attribute__((address_space(3))) void*)l, 16, 0, 0);
}

// Fragment layout (A and B operands, 16x16x32 f16 MFMA):
//   element (n, d) -> granule G = ((n>>4)*8 + (d>>5))*64 + ((d>>3)&3)*16 + (n&15),
//   half j = d&7 inside the 16B granule. Conflict-free ds_read_b128, linear gll16.

// ---------------- K0a: embedding -> fragment-layout fp16 hi/lo ---------------
__global__ void k_prep_frag(const float* __restrict__ emb, _Float16* __restrict__ BhF,
                            _Float16* __restrict__ BlF) {
    int gi = blockIdx.x * 256 + threadIdx.x;
    int kb = gi >> 9, s = (gi >> 6) & 7, dq = (gi >> 4) & 3, r = gi & 15;
    int code = kb * 16 + r;
    const float* src = emb + (size_t)code * DIM + s * 32 + dq * 8;
    float4 x0 = *(const float4*)(src);
    float4 x1 = *(const float4*)(src + 4);
    float xs[8] = {x0.x, x0.y, x0.z, x0.w, x1.x, x1.y, x1.z, x1.w};
    h8 hi, lo;
#pragma unroll
    for (int j = 0; j < 8; ++j) {
        _Float16 h = (_Float16)xs[j];
        hi[j] = h;
        lo[j] = (_Float16)(xs[j] - (float)h);
    }
    *(h8*)(BhF + (size_t)gi * 8) = hi;
    *(h8*)(BlF + (size_t)gi * 8) = lo;
}

// ---------------- K0b: e_sq ---------------------------------------------------
__global__ void k_esq(const float* __restrict__ emb, float* __restrict__ e_sq) {
    int t = threadIdx.x;
    int code = blockIdx.x * 4 + (t >> 6);
    int l = t & 63;
    float4 v = *(const float4*)(emb + (size_t)code * DIM + l * 4);
    float s = v.x * v.x + v.y * v.y + v.z * v.z + v.w * v.w;
#pragma unroll
    for (int off = 32; off >= 1; off >>= 1) s += __shfl_xor(s, off);
    if (l == 0) e_sq[code] = s;
}

// ------- K1: transpose z[B,C,H,W] -> enc[N,C] + fragment fp16 hi/lo ----------
__global__ void k_transpose(const float* __restrict__ z, float* __restrict__ enc,
                            _Float16* __restrict__ AhF, _Float16* __restrict__ AlF) {
    __shared__ float T[64][65];
    int blk = blockIdx.x;
    int b = blk >> 8;
    int rem = blk & 255;
    int c0 = (rem >> 6) * 64;
    int hw0 = (rem & 63) * 64;
    int t = threadIdx.x;
    const float* zp = z + (size_t)b * DIM * HWSZ;
    {
        int hw4 = (t & 15) * 4, cl = t >> 4;
#pragma unroll
        for (int i = 0; i < 4; ++i) {
            int c = cl + i * 16;
            float4 v = *(const float4*)(zp + (size_t)(c0 + c) * HWSZ + hw0 + hw4);
            T[c][hw4 + 0] = v.x; T[c][hw4 + 1] = v.y;
            T[c][hw4 + 2] = v.z; T[c][hw4 + 3] = v.w;
        }
    }
    __syncthreads();
    {
        int c4 = (t & 15) * 4, hwl = t >> 4;
#pragma unroll
        for (int i = 0; i < 4; ++i) {
            int hw = hwl + i * 16;
            float4 v;
            v.x = T[c4 + 0][hw]; v.y = T[c4 + 1][hw];
            v.z = T[c4 + 2][hw]; v.w = T[c4 + 3][hw];
            *(float4*)(enc + (size_t)(b * HWSZ + hw0 + hw) * DIM + c0 + c4) = v;
        }
    }
    {
        int base_nb = b * 256 + (hw0 >> 4);
#pragma unroll
        for (int i = 0; i < 2; ++i) {
            int gidx = i * 256 + t;
            int nbi = gidx >> 7, si = (gidx >> 6) & 1, dq = (gidx >> 4) & 3, r = gidx & 15;
            int hwl = nbi * 16 + r;
            int cl = si * 32 + dq * 8;
            h8 hi, lo;
#pragma unroll
            for (int j = 0; j < 8; ++j) {
                float x = T[cl + j][hwl];
                _Float16 h = (_Float16)x;
                hi[j] = h;
                lo[j] = (_Float16)(x - (float)h);
            }
            size_t G = (((size_t)(base_nb + nbi) * 8) + (c0 >> 5) + si) * 64 + dq * 16 + r;
            *(h8*)(AhF + G * 8) = hi;
            *(h8*)(AlF + G * 8) = lo;
        }
    }
}

// ---- K2: GEMM, m201-faithful 4-phase/K64-tile quadrant schedule -------------
// virtual K=768 = 12 K64-tiles (pass p=tau>>2: 0:AhBh 1:AhBl 2:AlBh).
// LDS: A[2db][2half][16KB] + B[2db][2half][16KB] = 128KB.
// Per phase: [ds_reads][stage unit][barrier][lgkmcnt0][setprio MFMA x16].
#define WAITV(n) asm volatile("s_waitcnt vmcnt(" #n ")" ::: "memory")
#define BARRIER __builtin_amdgcn_s_barrier()
#define PRIO1 __builtin_amdgcn_s_setprio(1)
#define PRIO0 __builtin_amdgcn_s_setprio(0)
#define LGKM0 do { asm volatile("s_waitcnt lgkmcnt(0)" ::: "memory"); \
                   __builtin_amdgcn_sched_barrier(0); } while (0)

extern __shared__ char SB[];

__global__ __launch_bounds__(512, 2)
void k_gemm_argmin(const _Float16* __restrict__ AhF, const _Float16* __restrict__ AlF,
                   const _Float16* __restrict__ BhF, const _Float16* __restrict__ BlF,
                   const float* __restrict__ e_sq,
                   float* __restrict__ pV1, int* __restrict__ pI1) {
    int gid = blockIdx.x;
    // rchunk-major: 8-MB A chunks (32 rowTiles) reused across all 4 colTiles
    int grp = gid >> 7;
    int colTile = (gid >> 5) & 3;
    int rowTile = grp * 32 + (gid & 31);
    int r0 = rowTile * 256, c0 = colTile * 256;
    int t = threadIdx.x;
    int w = t >> 6, l = t & 63;           // 8 waves
    int wm = w >> 2, wn = w & 3;          // wave tile 128 rows x 64 cols
    int l16 = l & 15, lhi = l >> 4;

    const char* gAh = (const char*)AhF + (((size_t)(rowTile * 16 + w)) << 13) + (l << 4);
    const char* gAl = (const char*)AlF + (((size_t)(rowTile * 16 + w)) << 13) + (l << 4);
    const char* gBh = (const char*)BhF + (((size_t)(colTile * 16 + w)) << 13) + (l << 4);
    const char* gBl = (const char*)BlF + (((size_t)(colTile * 16 + w)) << 13) + (l << 4);

// stage unit = one operand-half of K64-tile tau (16KB; 2 gll16/thread).
// wave w covers nb-local w of the half; the two k-steps go to [w][k] 1KB slots.
#define ST_A(tau, h) do { \
    const char* s_ = (((tau) >> 2) == 2) ? gAl : gAh; \
    const int s0_ = ((tau) & 3) * 2; \
    char* d_ = SB + (((tau) & 1) * 32768) + ((h) * 16384) + ((2 * w) << 10); \
    gll16(s_ + ((h) << 16) + (s0_ << 10), d_); \
    gll16(s_ + ((h) << 16) + ((s0_ + 1) << 10), d_ + 1024); \
} while (0)

#define ST_B(tau, h) do { \
    const char* s_ = (((tau) >> 2) == 1) ? gBl : gBh; \
    const int s0_ = ((tau) & 3) * 2; \
    char* d_ = SB + 65536 + (((tau) & 1) * 32768) + ((h) * 16384) + ((2 * w) << 10); \
    gll16(s_ + ((h) << 16) + (s0_ << 10), d_); \
    gll16(s_ + ((h) << 16) + ((s0_ + 1) << 10), d_ + 1024); \
} while (0)

// quadrant reads: A (8 ds_read_b128), B (4 ds_read_b128)
#define RD_A(tau, qm) { \
    const char* p_ = SB + (((tau) & 1) * 32768) + (wm * 16384); \
    _Pragma("unroll") for (int mf = 0; mf < 4; ++mf) { \
        aR[mf * 2 + 0] = *(const h8*)(p_ + (((((qm) * 4 + mf) * 2) + 0) << 10) + (l << 4)); \
        aR[mf * 2 + 1] = *(const h8*)(p_ + (((((qm) * 4 + mf) * 2) + 1) << 10) + (l << 4)); } }

#define RD_B(tau, qn, bR) { \
    const char* p_ = SB + 65536 + (((tau) & 1) * 32768) + ((wn >> 1) * 16384); \
    _Pragma("unroll") for (int nf = 0; nf < 2; ++nf) { \
        const int nb_ = ((wn & 1) * 4 + (qn) * 2 + nf) * 2; \
        bR[nf * 2 + 0] = *(const h8*)(p_ + ((nb_ + 0) << 10) + (l << 4)); \
        bR[nf * 2 + 1] = *(const h8*)(p_ + ((nb_ + 1) << 10) + (l << 4)); } }

#define MM(qm, qn, bR) { _Pragma("unroll") for (int mf = 0; mf < 4; ++mf) \
    _Pragma("unroll") for (int nf = 0; nf < 2; ++nf) { \
        acc[qm][qn][mf][nf] = __builtin_amdgcn_mfma_f32_16x16x32_f16(aR[mf*2+0], bR[nf*2+0], acc[qm][qn][mf][nf], 0, 0, 0); \
        acc[qm][qn][mf][nf] = __builtin_amdgcn_mfma_f32_16x16x32_f16(aR[mf*2+1], bR[nf*2+1], acc[qm][qn][mf][nf], 0, 0, 0); } }

// one K64-tile = 4 quadrant phases (0,0)(0,1)(1,1)(1,0).
// stage slots proven race-free: target's last ds_read completed before an
// earlier lgkmcnt(0)+barrier. vmcnt(6) before the barrier preceding the next
// tile's reads (cross-wave arrival via waitv->barrier).
#define TILE(tau) { \
    RD_A(tau, 0); RD_B(tau, 0, bQ0); \
    if ((tau) + 1 < 12) { ST_A((tau) + 1, 1); } \
    BARRIER; LGKM0; PRIO1; MM(0, 0, bQ0); PRIO0; BARRIER; \
    RD_B(tau, 1, bQ1); \
    BARRIER; LGKM0; PRIO1; MM(0, 1, bQ1); PRIO0; BARRIER; \
    RD_A(tau, 1); \
    if ((tau) + 2 < 12) { ST_B((tau) + 2, 0); } \
    BARRIER; LGKM0; PRIO1; MM(1, 1, bQ1); PRIO0; BARRIER; \
    if ((tau) + 2 < 12) { ST_B((tau) + 2, 1); ST_A((tau) + 2, 0); } \
    PRIO1; MM(1, 0, bQ0); PRIO0; \
    if ((tau) < 10) { WAITV(6); } else { WAITV(0); } \
    BARRIER; }

    f4 acc[2][2][4][2];
#pragma unroll
    for (int i = 0; i < 2; ++i)
#pragma unroll
        for (int j = 0; j < 2; ++j)
#pragma unroll
            for (int m = 0; m < 4; ++m)
#pragma unroll
                for (int n = 0; n < 2; ++n) acc[i][j][m][n] = (f4)0.0f;

    h8 aR[8], bQ0[4], bQ1[4];

    // prologue: 7 units (tile 0 complete + tile 1 minus A-h1); then the loop's
    // steady pattern supplies A(1,h1) at tile0.ph1.
    ST_B(0, 0); ST_B(0, 1); ST_A(0, 0); ST_A(0, 1);
    ST_B(1, 0); ST_B(1, 1); ST_A(1, 0);
    WAITV(6); BARRIER;

    TILE(0)  TILE(1)  TILE(2)  TILE(3)
    TILE(4)  TILE(5)  TILE(6)  TILE(7)
    TILE(8)  TILE(9)  TILE(10) TILE(11)

    // ---- scores + per-row argmin over this block's 256 codes ----
    float* smV = (float*)SB;          // [4][256] — overlays A db0 (tile 11 = db1)
    int* smI = (int*)(SB + 4096);     // [4][256]

    float esq[4];
#pragma unroll
    for (int qn = 0; qn < 2; ++qn)
#pragma unroll
        for (int nf = 0; nf < 2; ++nf)
            esq[qn * 2 + nf] = e_sq[c0 + wn * 64 + qn * 32 + nf * 16 + l16];

#pragma unroll
    for (int qm = 0; qm < 2; ++qm) {
#pragma unroll
        for (int mf = 0; mf < 4; ++mf) {
#pragma unroll
            for (int rg = 0; rg < 4; ++rg) {
                float bestV = 3.4e38f;
                int bestI = 0;
#pragma unroll
                for (int qn = 0; qn < 2; ++qn)
#pragma unroll
                    for (int nf = 0; nf < 2; ++nf) {
                        float v = esq[qn * 2 + nf] - 2.0f * acc[qm][qn][mf][nf][rg];
                        int ci = c0 + wn * 64 + qn * 32 + nf * 16 + l16;
                        if (v < bestV || (v == bestV && ci < bestI)) { bestV = v; bestI = ci; }
                    }
#pragma unroll
                for (int off = 1; off < 16; off <<= 1) {
                    float vv = __shfl_xor(bestV, off);
                    int ii = __shfl_xor(bestI, off);
                    if (vv < bestV || (vv == bestV && ii < bestI)) { bestV = vv; bestI = ii; }
                }
                if (l16 == 0) {
                    int rloc = wm * 128 + qm * 64 + mf * 16 + lhi * 4 + rg;
                    smV[wn * 256 + rloc] = bestV;
                    smI[wn * 256 + rloc] = bestI;
                }
            }
        }
    }
    __syncthreads();
    if (t < 256) {
        float bestV = smV[t];
        int bestI = smI[t];
#pragma unroll
        for (int wn2 = 1; wn2 < 4; ++wn2) {
            float v = smV[wn2 * 256 + t];
            int i2 = smI[wn2 * 256 + t];
            if (v < bestV || (v == bestV && i2 < bestI)) { bestV = v; bestI = i2; }
        }
        pV1[colTile * N_TOK + r0 + t] = bestV;
        pI1[colTile * N_TOK + r0 + t] = bestI;
    }
}

// ---- K3: fused epilogue: combine -> out2, gather out1, transpose out3 -------
__global__ void k_final_all(const float* __restrict__ pV1, const int* __restrict__ pI1,
                            const float* __restrict__ emb,
                            float* __restrict__ out2, float* __restrict__ out1,
                            float* __restrict__ out3) {
    __shared__ int sidx[256];
    __shared__ float E[32][257];
    int t = threadIdx.x;
    int n0 = blockIdx.x * 256;
    int n = n0 + t;
    float v1 = pV1[n];
    int i1 = pI1[n];
#pragma unroll
    for (int ct = 1; ct < 4; ++ct) {
        float a1 = pV1[ct * N_TOK + n];
        int ai = pI1[ct * N_TOK + n];
        if (a1 < v1 || (a1 == v1 && ai < i1)) { v1 = a1; i1 = ai; }
    }
    out2[n] = (float)i1;
    sidx[t] = i1;
    __syncthreads();
    {
        int rr = t >> 2, q = t & 3;
#pragma unroll
        for (int i = 0; i < 4; ++i) {
            int r = i * 64 + rr;
            int idx = sidx[r];
            const float* src = emb + (size_t)idx * DIM + q * 64;
            float* dst = out1 + (size_t)(n0 + r) * DIM + q * 64;
#pragma unroll
            for (int j = 0; j < 16; ++j)
                *(float4*)(dst + j * 4) = *(const float4*)(src + j * 4);
        }
    }
    int b = n0 >> 12;
    int hw0b = n0 & 4095;
    for (int sub = 0; sub < 8; ++sub) {
        __syncthreads();
        {
            int r = t >> 3, oct = t & 7;
            int idx = sidx[sub * 32 + r];
            const float* src = emb + (size_t)idx * DIM + oct * 32;
#pragma unroll
            for (int i = 0; i < 8; ++i) {
                float4 v = *(const float4*)(src + i * 4);
                E[r][oct * 32 + i * 4 + 0] = v.x;
                E[r][oct * 32 + i * 4 + 1] = v.y;
                E[r][oct * 32 + i * 4 + 2] = v.z;
                E[r][oct * 32 + i * 4 + 3] = v.w;
            }
        }
        __syncthreads();
        {
            int w = t >> 6, l = t & 63;
            int ch = l >> 5, hw = l & 31;
            float* dst = out3 + (size_t)b * DIM * HWSZ + hw0b + sub * 32 + hw;
#pragma unroll
            for (int it = 0; it < 32; ++it) {
                int c = w * 64 + it * 2 + ch;
                dst[(size_t)c * HWSZ] = E[hw][c];
            }
        }
    }
}

extern "C" void kernel_launch(void* const* d_in, const int* in_sizes, int n_in,
                              void* d_out, int out_size, void* d_ws, size_t ws_size,
                              hipStream_t stream) {
    const float* z = (const float*)d_in[0];
    const float* emb = (const float*)d_in[1];
    float* out = (float*)d_out;
    float* out0 = out;                    // encoded_flat  [65536,256]
    float* out1 = out + 16777216;         // quantized_flat[65536,256]
    float* out2 = out + 33554432;         // indices       [65536] (as float)
    float* out3 = out + 33619968;         // quantized     [16,256,64,64]

    // A-operand fp16 hi/lo scratch fills the out1 region (64 MB); out1 is
    // written afterwards by k_final_all.
    _Float16* AhF = (_Float16*)out1;
    _Float16* AlF = (_Float16*)(out1 + 8388608);

    char* ws = (char*)d_ws;
    _Float16* BhF = (_Float16*)(ws);                 // 512 KB
    _Float16* BlF = (_Float16*)(ws + 524288);        // 512 KB
    float* e_sq = (float*)(ws + 1048576);            // 4 KB
    float* pV1 = (float*)(ws + 1052672);             // 1 MB
    int* pI1 = (int*)(ws + 2101248);                 // 1 MB

    hipFuncSetAttribute((const void*)k_gemm_argmin,
                        hipFuncAttributeMaxDynamicSharedMemorySize, 131072);

    k_prep_frag<<<128, 256, 0, stream>>>(emb, BhF, BlF);
    k_esq<<<256, 256, 0, stream>>>(emb, e_sq);
    k_transpose<<<4096, 256, 0, stream>>>(z, out0, AhF, AlF);
    k_gemm_argmin<<<1024, 512, 131072, stream>>>(AhF, AlF, BhF, BlF, e_sq, pV1, pI1);
    k_final_all<<<256, 256, 0, stream>>>(pV1, pI1, emb, out2, out1, out3);
}

// Round 16
// 221.840 us; speedup vs baseline: 1.2539x; 1.0837x over previous
//
#include <hip/hip_runtime.h>
#include <hip/hip_bf16.h>

typedef _Float16 h8 __attribute__((ext_vector_type(8)));
typedef float f4 __attribute__((ext_vector_type(4)));

#define N_TOK 65536
#define DIM 256
#define KCODES 1024
#define HWSZ 4096

// async global->LDS, 16B per lane. LDS dest = wave-uniform base + lane*16.
__device__ __forceinline__ void gll16(const void* g, void* l) {
    __builtin_amdgcn_global_load_lds((const __attribute__((address_space(1))) void*)g,
                                     (__attribute__((address_space(3))) void*)l, 16, 0, 0);
}

// Fragment layout (A and B operands, 16x16x32 f16 MFMA):
//   element (n, d) -> granule G = ((n>>4)*8 + (d>>5))*64 + ((d>>3)&3)*16 + (n&15),
//   half j = d&7 inside the 16B granule. Conflict-free ds_read_b128, linear gll16.

// ---------------- K0a: embedding -> fragment-layout fp16 hi/lo ---------------
__global__ void k_prep_frag(const float* __restrict__ emb, _Float16* __restrict__ BhF,
                            _Float16* __restrict__ BlF) {
    int gi = blockIdx.x * 256 + threadIdx.x;
    int kb = gi >> 9, s = (gi >> 6) & 7, dq = (gi >> 4) & 3, r = gi & 15;
    int code = kb * 16 + r;
    const float* src = emb + (size_t)code * DIM + s * 32 + dq * 8;
    float4 x0 = *(const float4*)(src);
    float4 x1 = *(const float4*)(src + 4);
    float xs[8] = {x0.x, x0.y, x0.z, x0.w, x1.x, x1.y, x1.z, x1.w};
    h8 hi, lo;
#pragma unroll
    for (int j = 0; j < 8; ++j) {
        _Float16 h = (_Float16)xs[j];
        hi[j] = h;
        lo[j] = (_Float16)(xs[j] - (float)h);
    }
    *(h8*)(BhF + (size_t)gi * 8) = hi;
    *(h8*)(BlF + (size_t)gi * 8) = lo;
}

// ---------------- K0b: e_sq ---------------------------------------------------
__global__ void k_esq(const float* __restrict__ emb, float* __restrict__ e_sq) {
    int t = threadIdx.x;
    int code = blockIdx.x * 4 + (t >> 6);
    int l = t & 63;
    float4 v = *(const float4*)(emb + (size_t)code * DIM + l * 4);
    float s = v.x * v.x + v.y * v.y + v.z * v.z + v.w * v.w;
#pragma unroll
    for (int off = 32; off >= 1; off >>= 1) s += __shfl_xor(s, off);
    if (l == 0) e_sq[code] = s;
}

// ------- K1: transpose z[B,C,H,W] -> enc[N,C] + fragment fp16 hi/lo ----------
__global__ void k_transpose(const float* __restrict__ z, float* __restrict__ enc,
                            _Float16* __restrict__ AhF, _Float16* __restrict__ AlF) {
    __shared__ float T[64][65];
    int blk = blockIdx.x;
    int b = blk >> 8;
    int rem = blk & 255;
    int c0 = (rem >> 6) * 64;
    int hw0 = (rem & 63) * 64;
    int t = threadIdx.x;
    const float* zp = z + (size_t)b * DIM * HWSZ;
    {
        int hw4 = (t & 15) * 4, cl = t >> 4;
#pragma unroll
        for (int i = 0; i < 4; ++i) {
            int c = cl + i * 16;
            float4 v = *(const float4*)(zp + (size_t)(c0 + c) * HWSZ + hw0 + hw4);
            T[c][hw4 + 0] = v.x; T[c][hw4 + 1] = v.y;
            T[c][hw4 + 2] = v.z; T[c][hw4 + 3] = v.w;
        }
    }
    __syncthreads();
    {
        int c4 = (t & 15) * 4, hwl = t >> 4;
#pragma unroll
        for (int i = 0; i < 4; ++i) {
            int hw = hwl + i * 16;
            float4 v;
            v.x = T[c4 + 0][hw]; v.y = T[c4 + 1][hw];
            v.z = T[c4 + 2][hw]; v.w = T[c4 + 3][hw];
            *(float4*)(enc + (size_t)(b * HWSZ + hw0 + hw) * DIM + c0 + c4) = v;
        }
    }
    {
        int base_nb = b * 256 + (hw0 >> 4);
#pragma unroll
        for (int i = 0; i < 2; ++i) {
            int gidx = i * 256 + t;
            int nbi = gidx >> 7, si = (gidx >> 6) & 1, dq = (gidx >> 4) & 3, r = gidx & 15;
            int hwl = nbi * 16 + r;
            int cl = si * 32 + dq * 8;
            h8 hi, lo;
#pragma unroll
            for (int j = 0; j < 8; ++j) {
                float x = T[cl + j][hwl];
                _Float16 h = (_Float16)x;
                hi[j] = h;
                lo[j] = (_Float16)(x - (float)h);
            }
            size_t G = (((size_t)(base_nb + nbi) * 8) + (c0 >> 5) + si) * 64 + dq * 16 + r;
            *(h8*)(AhF + G * 8) = hi;
            *(h8*)(AlF + G * 8) = lo;
        }
    }
}

// ---- K2: GEMM (fp16 split, 3 passes), merged-step phases, 2-step ring -------
// (R11 verbatim: best measured structure, 120.7 us, 858 TF effective)
#define WAITV(n) asm volatile("s_waitcnt vmcnt(" #n ")" ::: "memory")
#define BARRIER __builtin_amdgcn_s_barrier()
#define PRIO1 __builtin_amdgcn_s_setprio(1)
#define PRIO0 __builtin_amdgcn_s_setprio(0)

extern __shared__ char SB[];   // 2 step-bufs x 64 KB: [Ah 16K][Bh 16K][Al 16K][Bl 16K]

__global__ __launch_bounds__(1024)
void k_gemm_argmin(const _Float16* __restrict__ AhF, const _Float16* __restrict__ AlF,
                   const _Float16* __restrict__ BhF, const _Float16* __restrict__ BlF,
                   const float* __restrict__ e_sq,
                   float* __restrict__ pV1, int* __restrict__ pI1) {
    int gid = blockIdx.x;
    // rchunk-major: 8-MB A chunks (32 rowTiles) reused across all 4 colTiles
    int grp = gid >> 7;
    int colTile = (gid >> 5) & 3;
    int rowTile = grp * 32 + (gid & 31);
    int r0 = rowTile * 256, c0 = colTile * 256;
    int t = threadIdx.x;
    int w = t >> 6, l = t & 63;           // 16 waves
    int wm = w >> 2, wn = w & 3;          // wave tile 64x64
    int l16 = l & 15, lhi = l >> 4;

    const char* gAh = (const char*)AhF + (((size_t)(rowTile * 16 + w)) << 13) + (l << 4);
    const char* gAl = (const char*)AlF + (((size_t)(rowTile * 16 + w)) << 13) + (l << 4);
    const char* gBh = (const char*)BhF + (((size_t)(colTile * 16 + w)) << 13) + (l << 4);
    const char* gBl = (const char*)BlF + (((size_t)(colTile * 16 + w)) << 13) + (l << 4);

// stage all 4 operand chunks of K-step s into ring buf s&1 (4 KB per wave)
#define ISSUE_S(s) do { \
    char* bp_ = SB + ((s) & 1) * 65536; \
    gll16(gAh + ((s) << 10), bp_ + (w << 10)); \
    gll16(gBh + ((s) << 10), bp_ + 16384 + (w << 10)); \
    gll16(gAl + ((s) << 10), bp_ + 32768 + (w << 10)); \
    gll16(gBl + ((s) << 10), bp_ + 49152 + (w << 10)); \
} while (0)

#define MFMA16(A_, B_) { _Pragma("unroll") for (int mf = 0; mf < 4; ++mf) \
    _Pragma("unroll") for (int nf = 0; nf < 4; ++nf) \
        acc[mf][nf] = __builtin_amdgcn_mfma_f32_16x16x32_f16(A_[mf], B_[nf], acc[mf][nf], 0, 0, 0); }

// one K-step: hh burst, then (bl read + hl burst), then (al read + lh burst).
#define PHASE(q, DO_ISSUE) { \
    WAITV(0); \
    BARRIER; \
    if (DO_ISSUE) ISSUE_S((q) + 1); \
    const char* bp_ = SB + ((q) & 1) * 65536; \
    _Pragma("unroll") for (int mf = 0; mf < 4; ++mf) \
        ah[mf] = *(const h8*)(bp_ + ((wm * 4 + mf) << 10) + (l << 4)); \
    _Pragma("unroll") for (int nf = 0; nf < 4; ++nf) \
        bh[nf] = *(const h8*)(bp_ + 16384 + ((wn * 4 + nf) << 10) + (l << 4)); \
    PRIO1; MFMA16(ah, bh); PRIO0; \
    { h8 xl[4]; \
      _Pragma("unroll") for (int nf = 0; nf < 4; ++nf) \
          xl[nf] = *(const h8*)(bp_ + 49152 + ((wn * 4 + nf) << 10) + (l << 4)); \
      PRIO1; MFMA16(ah, xl); PRIO0; \
      _Pragma("unroll") for (int mf = 0; mf < 4; ++mf) \
          xl[mf] = *(const h8*)(bp_ + 32768 + ((wm * 4 + mf) << 10) + (l << 4)); \
      PRIO1; MFMA16(xl, bh); PRIO0; } }

    f4 acc[4][4];
#pragma unroll
    for (int i = 0; i < 4; ++i)
#pragma unroll
        for (int j = 0; j < 4; ++j) acc[i][j] = (f4)0.0f;

    h8 ah[4], bh[4];

    ISSUE_S(0);   // prologue: step 0 in flight

    PHASE(0, 1)  PHASE(1, 1)  PHASE(2, 1)  PHASE(3, 1)
    PHASE(4, 1)  PHASE(5, 1)  PHASE(6, 1)  PHASE(7, 0)

    // ---- scores + per-row argmin over this block's 256 codes ----
    float* smV = (float*)SB;          // [4][256]
    int* smI = (int*)(SB + 4096);     // [4][256]

    float esq[4];
#pragma unroll
    for (int nf = 0; nf < 4; ++nf) esq[nf] = e_sq[c0 + wn * 64 + nf * 16 + l16];

#pragma unroll
    for (int mf = 0; mf < 4; ++mf) {
#pragma unroll
        for (int rg = 0; rg < 4; ++rg) {
            float bestV = 3.4e38f;
            int bestI = 0;
#pragma unroll
            for (int nf = 0; nf < 4; ++nf) {
                float v = esq[nf] - 2.0f * acc[mf][nf][rg];
                int ci = c0 + wn * 64 + nf * 16 + l16;
                if (v < bestV || (v == bestV && ci < bestI)) { bestV = v; bestI = ci; }
            }
#pragma unroll
            for (int off = 1; off < 16; off <<= 1) {
                float vv = __shfl_xor(bestV, off);
                int ii = __shfl_xor(bestI, off);
                if (vv < bestV || (vv == bestV && ii < bestI)) { bestV = vv; bestI = ii; }
            }
            if (l16 == 0) {
                int rloc = wm * 64 + mf * 16 + lhi * 4 + rg;
                smV[wn * 256 + rloc] = bestV;
                smI[wn * 256 + rloc] = bestI;
            }
        }
    }
    __syncthreads();
    if (t < 256) {
        float bestV = smV[t];
        int bestI = smI[t];
#pragma unroll
        for (int wn2 = 1; wn2 < 4; ++wn2) {
            float v = smV[wn2 * 256 + t];
            int i2 = smI[wn2 * 256 + t];
            if (v < bestV || (v == bestV && i2 < bestI)) { bestV = v; bestI = i2; }
        }
        pV1[colTile * N_TOK + r0 + t] = bestV;
        pI1[colTile * N_TOK + r0 + t] = bestI;
    }
}

// ---- K3: fused epilogue (64 tokens/block, 4 blocks/CU): combine -> out2,
//          gather out1, transpose out3 ---------------------------------------
__global__ void k_final_all(const float* __restrict__ pV1, const int* __restrict__ pI1,
                            const float* __restrict__ emb,
                            float* __restrict__ out2, float* __restrict__ out1,
                            float* __restrict__ out3) {
    __shared__ int sidx[64];
    __shared__ float E[32][257];
    int t = threadIdx.x;
    int n0 = blockIdx.x * 64;
    if (t < 64) {
        int n = n0 + t;
        float v1 = pV1[n];
        int i1 = pI1[n];
#pragma unroll
        for (int ct = 1; ct < 4; ++ct) {
            float a1 = pV1[ct * N_TOK + n];
            int ai = pI1[ct * N_TOK + n];
            if (a1 < v1 || (a1 == v1 && ai < i1)) { v1 = a1; i1 = ai; }
        }
        out2[n] = (float)i1;
        sidx[t] = i1;
    }
    __syncthreads();
    // out1: gather embedding rows (64 rows, 4 threads/row)
    {
        int r = t >> 2, q = t & 3;
        int idx = sidx[r];
        const float* src = emb + (size_t)idx * DIM + q * 64;
        float* dst = out1 + (size_t)(n0 + r) * DIM + q * 64;
#pragma unroll
        for (int j = 0; j < 16; ++j)
            *(float4*)(dst + j * 4) = *(const float4*)(src + j * 4);
    }
    // out3: transposed writes, 2 sub-chunks of 32 tokens
    int b = n0 >> 12;
    int hw0b = n0 & 4095;
    for (int sub = 0; sub < 2; ++sub) {
        __syncthreads();
        {
            int r = t >> 3, oct = t & 7;
            int idx = sidx[sub * 32 + r];
            const float* src = emb + (size_t)idx * DIM + oct * 32;
#pragma unroll
            for (int i = 0; i < 8; ++i) {
                float4 v = *(const float4*)(src + i * 4);
                E[r][oct * 32 + i * 4 + 0] = v.x;
                E[r][oct * 32 + i * 4 + 1] = v.y;
                E[r][oct * 32 + i * 4 + 2] = v.z;
                E[r][oct * 32 + i * 4 + 3] = v.w;
            }
        }
        __syncthreads();
        {
            int w = t >> 6, l = t & 63;
            int ch = l >> 5, hw = l & 31;
            float* dst = out3 + (size_t)b * DIM * HWSZ + hw0b + sub * 32 + hw;
#pragma unroll
            for (int it = 0; it < 32; ++it) {
                int c = w * 64 + it * 2 + ch;
                dst[(size_t)c * HWSZ] = E[hw][c];
            }
        }
    }
}

extern "C" void kernel_launch(void* const* d_in, const int* in_sizes, int n_in,
                              void* d_out, int out_size, void* d_ws, size_t ws_size,
                              hipStream_t stream) {
    const float* z = (const float*)d_in[0];
    const float* emb = (const float*)d_in[1];
    float* out = (float*)d_out;
    float* out0 = out;                    // encoded_flat  [65536,256]
    float* out1 = out + 16777216;         // quantized_flat[65536,256]
    float* out2 = out + 33554432;         // indices       [65536] (as float)
    float* out3 = out + 33619968;         // quantized     [16,256,64,64]

    // A-operand fp16 hi/lo scratch fills the out1 region (64 MB); out1 is
    // written afterwards by k_final_all.
    _Float16* AhF = (_Float16*)out1;
    _Float16* AlF = (_Float16*)(out1 + 8388608);

    char* ws = (char*)d_ws;
    _Float16* BhF = (_Float16*)(ws);                 // 512 KB
    _Float16* BlF = (_Float16*)(ws + 524288);        // 512 KB
    float* e_sq = (float*)(ws + 1048576);            // 4 KB
    float* pV1 = (float*)(ws + 1052672);             // 1 MB
    int* pI1 = (int*)(ws + 2101248);                 // 1 MB

    hipFuncSetAttribute((const void*)k_gemm_argmin,
                        hipFuncAttributeMaxDynamicSharedMemorySize, 131072);

    k_prep_frag<<<128, 256, 0, stream>>>(emb, BhF, BlF);
    k_esq<<<256, 256, 0, stream>>>(emb, e_sq);
    k_transpose<<<4096, 256, 0, stream>>>(z, out0, AhF, AlF);
    k_gemm_argmin<<<1024, 1024, 131072, stream>>>(AhF, AlF, BhF, BlF, e_sq, pV1, pI1);
    k_final_all<<<1024, 256, 0, stream>>>(pV1, pI1, emb, out2, out1, out3);
}

// Round 17
// 205.300 us; speedup vs baseline: 1.3549x; 1.0806x over previous
//
#include <hip/hip_runtime.h>
#include <hip/hip_bf16.h>

typedef _Float16 h8 __attribute__((ext_vector_type(8)));
typedef float f4 __attribute__((ext_vector_type(4)));

#define N_TOK 65536
#define DIM 256
#define KCODES 1024
#define HWSZ 4096

// async global->LDS, 16B per lane. LDS dest = wave-uniform base + lane*16.
__device__ __forceinline__ void gll16(const void* g, void* l) {
    __builtin_amdgcn_global_load_lds((const __attribute__((address_space(1))) void*)g,
                                     (__attribute__((address_space(3))) void*)l, 16, 0, 0);
}

// Fragment layout (A and B operands, 16x16x32 f16 MFMA):
//   element (n, d) -> granule G = ((n>>4)*8 + (d>>5))*64 + ((d>>3)&3)*16 + (n&15),
//   half j = d&7 inside the 16B granule. Conflict-free ds_read_b128, linear gll16.

// ---------------- K0a: embedding -> fragment-layout fp16 hi/lo ---------------
__global__ void k_prep_frag(const float* __restrict__ emb, _Float16* __restrict__ BhF,
                            _Float16* __restrict__ BlF) {
    int gi = blockIdx.x * 256 + threadIdx.x;
    int kb = gi >> 9, s = (gi >> 6) & 7, dq = (gi >> 4) & 3, r = gi & 15;
    int code = kb * 16 + r;
    const float* src = emb + (size_t)code * DIM + s * 32 + dq * 8;
    float4 x0 = *(const float4*)(src);
    float4 x1 = *(const float4*)(src + 4);
    float xs[8] = {x0.x, x0.y, x0.z, x0.w, x1.x, x1.y, x1.z, x1.w};
    h8 hi, lo;
#pragma unroll
    for (int j = 0; j < 8; ++j) {
        _Float16 h = (_Float16)xs[j];
        hi[j] = h;
        lo[j] = (_Float16)(xs[j] - (float)h);
    }
    *(h8*)(BhF + (size_t)gi * 8) = hi;
    *(h8*)(BlF + (size_t)gi * 8) = lo;
}

// ---------------- K0b: e_sq ---------------------------------------------------
__global__ void k_esq(const float* __restrict__ emb, float* __restrict__ e_sq) {
    int t = threadIdx.x;
    int code = blockIdx.x * 4 + (t >> 6);
    int l = t & 63;
    float4 v = *(const float4*)(emb + (size_t)code * DIM + l * 4);
    float s = v.x * v.x + v.y * v.y + v.z * v.z + v.w * v.w;
#pragma unroll
    for (int off = 32; off >= 1; off >>= 1) s += __shfl_xor(s, off);
    if (l == 0) e_sq[code] = s;
}

// ------- K1: transpose z[B,C,H,W] -> enc[N,C] + fragment fp16 hi/lo ----------
__global__ void k_transpose(const float* __restrict__ z, float* __restrict__ enc,
                            _Float16* __restrict__ AhF, _Float16* __restrict__ AlF) {
    __shared__ float T[64][65];
    int blk = blockIdx.x;
    int b = blk >> 8;
    int rem = blk & 255;
    int c0 = (rem >> 6) * 64;
    int hw0 = (rem & 63) * 64;
    int t = threadIdx.x;
    const float* zp = z + (size_t)b * DIM * HWSZ;
    {
        int hw4 = (t & 15) * 4, cl = t >> 4;
#pragma unroll
        for (int i = 0; i < 4; ++i) {
            int c = cl + i * 16;
            float4 v = *(const float4*)(zp + (size_t)(c0 + c) * HWSZ + hw0 + hw4);
            T[c][hw4 + 0] = v.x; T[c][hw4 + 1] = v.y;
            T[c][hw4 + 2] = v.z; T[c][hw4 + 3] = v.w;
        }
    }
    __syncthreads();
    {
        int c4 = (t & 15) * 4, hwl = t >> 4;
#pragma unroll
        for (int i = 0; i < 4; ++i) {
            int hw = hwl + i * 16;
            float4 v;
            v.x = T[c4 + 0][hw]; v.y = T[c4 + 1][hw];
            v.z = T[c4 + 2][hw]; v.w = T[c4 + 3][hw];
            *(float4*)(enc + (size_t)(b * HWSZ + hw0 + hw) * DIM + c0 + c4) = v;
        }
    }
    {
        int base_nb = b * 256 + (hw0 >> 4);
#pragma unroll
        for (int i = 0; i < 2; ++i) {
            int gidx = i * 256 + t;
            int nbi = gidx >> 7, si = (gidx >> 6) & 1, dq = (gidx >> 4) & 3, r = gidx & 15;
            int hwl = nbi * 16 + r;
            int cl = si * 32 + dq * 8;
            h8 hi, lo;
#pragma unroll
            for (int j = 0; j < 8; ++j) {
                float x = T[cl + j][hwl];
                _Float16 h = (_Float16)x;
                hi[j] = h;
                lo[j] = (_Float16)(x - (float)h);
            }
            size_t G = (((size_t)(base_nb + nbi) * 8) + (c0 >> 5) + si) * 64 + dq * 16 + r;
            *(h8*)(AhF + G * 8) = hi;
            *(h8*)(AlF + G * 8) = lo;
        }
    }
}

// ---- K2: GEMM (fp16 split, 3 passes), merged-step phases, 2-step ring -------
#define WAITV(n) asm volatile("s_waitcnt vmcnt(" #n ")" ::: "memory")
#define BARRIER __builtin_amdgcn_s_barrier()
#define PRIO1 __builtin_amdgcn_s_setprio(1)
#define PRIO0 __builtin_amdgcn_s_setprio(0)

extern __shared__ char SB[];   // 2 step-bufs x 64 KB: [Ah 16K][Bh 16K][Al 16K][Bl 16K]

__global__ __launch_bounds__(1024)
void k_gemm_argmin(const _Float16* __restrict__ AhF, const _Float16* __restrict__ AlF,
                   const _Float16* __restrict__ BhF, const _Float16* __restrict__ BlF,
                   const float* __restrict__ e_sq,
                   float* __restrict__ pV1, int* __restrict__ pI1) {
    int gid = blockIdx.x;
    // rchunk-major: 8-MB A chunks (32 rowTiles) reused across all 4 colTiles
    int grp = gid >> 7;
    int colTile = (gid >> 5) & 3;
    int rowTile = grp * 32 + (gid & 31);
    int r0 = rowTile * 256, c0 = colTile * 256;
    int t = threadIdx.x;
    int w = t >> 6, l = t & 63;           // 16 waves
    int wm = w >> 2, wn = w & 3;          // wave tile 64x64
    int l16 = l & 15, lhi = l >> 4;

    const char* gAh = (const char*)AhF + (((size_t)(rowTile * 16 + w)) << 13) + (l << 4);
    const char* gAl = (const char*)AlF + (((size_t)(rowTile * 16 + w)) << 13) + (l << 4);
    const char* gBh = (const char*)BhF + (((size_t)(colTile * 16 + w)) << 13) + (l << 4);
    const char* gBl = (const char*)BlF + (((size_t)(colTile * 16 + w)) << 13) + (l << 4);

// stage all 4 operand chunks of K-step s into ring buf s&1 (4 KB per wave)
#define ISSUE_S(s) do { \
    char* bp_ = SB + ((s) & 1) * 65536; \
    gll16(gAh + ((s) << 10), bp_ + (w << 10)); \
    gll16(gBh + ((s) << 10), bp_ + 16384 + (w << 10)); \
    gll16(gAl + ((s) << 10), bp_ + 32768 + (w << 10)); \
    gll16(gBl + ((s) << 10), bp_ + 49152 + (w << 10)); \
} while (0)

#define MFMA16(A_, B_) { _Pragma("unroll") for (int mf = 0; mf < 4; ++mf) \
    _Pragma("unroll") for (int nf = 0; nf < 4; ++nf) \
        acc[mf][nf] = __builtin_amdgcn_mfma_f32_16x16x32_f16(A_[mf], B_[nf], acc[mf][nf], 0, 0, 0); }

// one K-step: hh burst, then (bl read + hl burst), then (al read + lh burst).
// WAITV(0) drains this step's 4 loads (issued one full phase ago); single barrier.
#define PHASE(q, DO_ISSUE) { \
    WAITV(0); \
    BARRIER; \
    if (DO_ISSUE) ISSUE_S((q) + 1); \
    const char* bp_ = SB + ((q) & 1) * 65536; \
    _Pragma("unroll") for (int mf = 0; mf < 4; ++mf) \
        ah[mf] = *(const h8*)(bp_ + ((wm * 4 + mf) << 10) + (l << 4)); \
    _Pragma("unroll") for (int nf = 0; nf < 4; ++nf) \
        bh[nf] = *(const h8*)(bp_ + 16384 + ((wn * 4 + nf) << 10) + (l << 4)); \
    PRIO1; MFMA16(ah, bh); PRIO0; \
    { h8 xl[4]; \
      _Pragma("unroll") for (int nf = 0; nf < 4; ++nf) \
          xl[nf] = *(const h8*)(bp_ + 49152 + ((wn * 4 + nf) << 10) + (l << 4)); \
      PRIO1; MFMA16(ah, xl); PRIO0; \
      _Pragma("unroll") for (int mf = 0; mf < 4; ++mf) \
          xl[mf] = *(const h8*)(bp_ + 32768 + ((wm * 4 + mf) << 10) + (l << 4)); \
      PRIO1; MFMA16(xl, bh); PRIO0; } }

    f4 acc[4][4];
#pragma unroll
    for (int i = 0; i < 4; ++i)
#pragma unroll
        for (int j = 0; j < 4; ++j) acc[i][j] = (f4)0.0f;

    h8 ah[4], bh[4];

    ISSUE_S(0);   // prologue: step 0 in flight

    PHASE(0, 1)  PHASE(1, 1)  PHASE(2, 1)  PHASE(3, 1)
    PHASE(4, 1)  PHASE(5, 1)  PHASE(6, 1)  PHASE(7, 0)

    // ---- scores + per-row argmin over this block's 256 codes ----
    // scratch overlays ring buf 0 (phase 7 computed from buf 1)
    float* smV = (float*)SB;          // [4][256]
    int* smI = (int*)(SB + 4096);     // [4][256]

    float esq[4];
#pragma unroll
    for (int nf = 0; nf < 4; ++nf) esq[nf] = e_sq[c0 + wn * 64 + nf * 16 + l16];

#pragma unroll
    for (int mf = 0; mf < 4; ++mf) {
#pragma unroll
        for (int rg = 0; rg < 4; ++rg) {
            float bestV = 3.4e38f;
            int bestI = 0;
#pragma unroll
            for (int nf = 0; nf < 4; ++nf) {
                float v = esq[nf] - 2.0f * acc[mf][nf][rg];
                int ci = c0 + wn * 64 + nf * 16 + l16;
                if (v < bestV || (v == bestV && ci < bestI)) { bestV = v; bestI = ci; }
            }
#pragma unroll
            for (int off = 1; off < 16; off <<= 1) {
                float vv = __shfl_xor(bestV, off);
                int ii = __shfl_xor(bestI, off);
                if (vv < bestV || (vv == bestV && ii < bestI)) { bestV = vv; bestI = ii; }
            }
            if (l16 == 0) {
                int rloc = wm * 64 + mf * 16 + lhi * 4 + rg;
                smV[wn * 256 + rloc] = bestV;
                smI[wn * 256 + rloc] = bestI;
            }
        }
    }
    __syncthreads();
    if (t < 256) {
        float bestV = smV[t];
        int bestI = smI[t];
#pragma unroll
        for (int wn2 = 1; wn2 < 4; ++wn2) {
            float v = smV[wn2 * 256 + t];
            int i2 = smI[wn2 * 256 + t];
            if (v < bestV || (v == bestV && i2 < bestI)) { bestV = v; bestI = i2; }
        }
        pV1[colTile * N_TOK + r0 + t] = bestV;
        pI1[colTile * N_TOK + r0 + t] = bestI;
    }
}

// ---- K3: fused epilogue: combine -> out2, gather out1, transpose out3 -------
__global__ void k_final_all(const float* __restrict__ pV1, const int* __restrict__ pI1,
                            const float* __restrict__ emb,
                            float* __restrict__ out2, float* __restrict__ out1,
                            float* __restrict__ out3) {
    __shared__ int sidx[256];
    __shared__ float E[32][257];
    int t = threadIdx.x;
    int n0 = blockIdx.x * 256;
    int n = n0 + t;
    float v1 = pV1[n];
    int i1 = pI1[n];
#pragma unroll
    for (int ct = 1; ct < 4; ++ct) {
        float a1 = pV1[ct * N_TOK + n];
        int ai = pI1[ct * N_TOK + n];
        if (a1 < v1 || (a1 == v1 && ai < i1)) { v1 = a1; i1 = ai; }
    }
    out2[n] = (float)i1;
    sidx[t] = i1;
    __syncthreads();
    // out1: gather embedding rows
    {
        int rr = t >> 2, q = t & 3;
#pragma unroll
        for (int i = 0; i < 4; ++i) {
            int r = i * 64 + rr;
            int idx = sidx[r];
            const float* src = emb + (size_t)idx * DIM + q * 64;
            float* dst = out1 + (size_t)(n0 + r) * DIM + q * 64;
#pragma unroll
            for (int j = 0; j < 16; ++j)
                *(float4*)(dst + j * 4) = *(const float4*)(src + j * 4);
        }
    }
    // out3: transposed writes, 8 sub-chunks of 32 tokens
    int b = n0 >> 12;
    int hw0b = n0 & 4095;
    for (int sub = 0; sub < 8; ++sub) {
        __syncthreads();
        {
            int r = t >> 3, oct = t & 7;
            int idx = sidx[sub * 32 + r];
            const float* src = emb + (size_t)idx * DIM + oct * 32;
#pragma unroll
            for (int i = 0; i < 8; ++i) {
                float4 v = *(const float4*)(src + i * 4);
                E[r][oct * 32 + i * 4 + 0] = v.x;
                E[r][oct * 32 + i * 4 + 1] = v.y;
                E[r][oct * 32 + i * 4 + 2] = v.z;
                E[r][oct * 32 + i * 4 + 3] = v.w;
            }
        }
        __syncthreads();
        {
            int w = t >> 6, l = t & 63;
            int ch = l >> 5, hw = l & 31;
            float* dst = out3 + (size_t)b * DIM * HWSZ + hw0b + sub * 32 + hw;
#pragma unroll
            for (int it = 0; it < 32; ++it) {
                int c = w * 64 + it * 2 + ch;
                dst[(size_t)c * HWSZ] = E[hw][c];
            }
        }
    }
}

extern "C" void kernel_launch(void* const* d_in, const int* in_sizes, int n_in,
                              void* d_out, int out_size, void* d_ws, size_t ws_size,
                              hipStream_t stream) {
    const float* z = (const float*)d_in[0];
    const float* emb = (const float*)d_in[1];
    float* out = (float*)d_out;
    float* out0 = out;                    // encoded_flat  [65536,256]
    float* out1 = out + 16777216;         // quantized_flat[65536,256]
    float* out2 = out + 33554432;         // indices       [65536] (as float)
    float* out3 = out + 33619968;         // quantized     [16,256,64,64]

    // A-operand fp16 hi/lo scratch fills the out1 region (64 MB); out1 is
    // written afterwards by k_final_all.
    _Float16* AhF = (_Float16*)out1;
    _Float16* AlF = (_Float16*)(out1 + 8388608);

    char* ws = (char*)d_ws;
    _Float16* BhF = (_Float16*)(ws);                 // 512 KB
    _Float16* BlF = (_Float16*)(ws + 524288);        // 512 KB
    float* e_sq = (float*)(ws + 1048576);            // 4 KB
    float* pV1 = (float*)(ws + 1052672);             // 1 MB
    int* pI1 = (int*)(ws + 2101248);                 // 1 MB

    hipFuncSetAttribute((const void*)k_gemm_argmin,
                        hipFuncAttributeMaxDynamicSharedMemorySize, 131072);

    k_prep_frag<<<128, 256, 0, stream>>>(emb, BhF, BlF);
    k_esq<<<256, 256, 0, stream>>>(emb, e_sq);
    k_transpose<<<4096, 256, 0, stream>>>(z, out0, AhF, AlF);
    k_gemm_argmin<<<1024, 1024, 131072, stream>>>(AhF, AlF, BhF, BlF, e_sq, pV1, pI1);
    k_final_all<<<256, 256, 0, stream>>>(pV1, pI1, emb, out2, out1, out3);
}